// Round 2
// baseline (558.518 us; speedup 1.0000x reference)
//
#include <hip/hip_runtime.h>

// Streaming masked-|diff| mean over N=20M rows x 5 fp32 cols.
// Memory-bound: 480 MB read -> ~76 us @ 6.3 TB/s for our kernel's share.
// Stage 1: block-tiled. Each block stages 1024 rows (1280 float4 = 20 KB) into
//          LDS with perfectly coalesced float4 streams (lane i -> consecutive
//          16 B), then reads c0/c2/c4 at stride-5 LDS addressing
//          (gcd(5,32)=1 -> conflict-free across 32 banks, free 2-way wave64
//          aliasing). Block partials -> d_ws.
// Stage 2: single block reduces partials, writes mean to d_out[0].

#define NBLOCKS 2048
#define NTHREADS 256
#define ROWS_PER_TILE 1024           // NTHREADS * 4 rows
#define F4_PER_TILE 1280             // ROWS_PER_TILE * 5 floats / 4

__device__ __forceinline__ float row_term(float c0, float c2, float c4, float tgt) {
    float d = (fabsf(c4 - c2) < 0.1f) ? (c0 - c4) : (c0 - tgt);
    return fabsf(d);
}

__global__ __launch_bounds__(NTHREADS) void loss_partial(
    const float* __restrict__ in, const float* __restrict__ tg,
    float* __restrict__ partial, long long nrows)
{
    __shared__ float4 tile4[F4_PER_TILE];        // 20 KB
    float* tile = (float*)tile4;

    const float4* __restrict__ in4 = (const float4*)in;
    const int tid = threadIdx.x;

    float sum = 0.0f;

    const long long ntiles = nrows / ROWS_PER_TILE;
    for (long long t = blockIdx.x; t < ntiles; t += gridDim.x) {
        // coalesced global -> LDS staging: 5 x dwordx4 per thread,
        // consecutive lanes -> consecutive 16 B
        const float4* __restrict__ src = in4 + t * F4_PER_TILE;
        #pragma unroll
        for (int k = 0; k < 5; ++k)
            tile4[k * NTHREADS + tid] = src[k * NTHREADS + tid];
        __syncthreads();

        const long long rowbase = t * ROWS_PER_TILE;
        const float* __restrict__ tgb = tg + rowbase;
        #pragma unroll
        for (int j = 0; j < 4; ++j) {
            const int r = tid + j * NTHREADS;          // row within tile
            const float c0 = tile[5 * r + 0];
            const float c2 = tile[5 * r + 2];
            const float c4 = tile[5 * r + 4];
            const float tv = tgb[r];                   // coalesced scalar load
            sum += row_term(c0, c2, c4, tv);
        }
        __syncthreads();
    }

    // tail rows (nrows % ROWS_PER_TILE), direct scalar path
    {
        const long long start = ntiles * ROWS_PER_TILE;
        const long long gtid = (long long)blockIdx.x * NTHREADS + tid;
        const long long gstride = (long long)gridDim.x * NTHREADS;
        for (long long r = start + gtid; r < nrows; r += gstride)
            sum += row_term(in[5 * r + 0], in[5 * r + 2], in[5 * r + 4], tg[r]);
    }

    // wave64 reduce
    #pragma unroll
    for (int off = 32; off > 0; off >>= 1)
        sum += __shfl_down(sum, off, 64);

    __shared__ float wsum[NTHREADS / 64];
    const int lane = tid & 63;
    const int wave = tid >> 6;
    if (lane == 0) wsum[wave] = sum;
    __syncthreads();
    if (tid == 0) {
        float s = 0.0f;
        #pragma unroll
        for (int w = 0; w < NTHREADS / 64; ++w) s += wsum[w];
        partial[blockIdx.x] = s;
    }
}

__global__ __launch_bounds__(NTHREADS) void loss_final(
    const float* __restrict__ partial, int nparts,
    float* __restrict__ out, long long nrows)
{
    float sum = 0.0f;
    for (int i = threadIdx.x; i < nparts; i += NTHREADS) sum += partial[i];

    #pragma unroll
    for (int off = 32; off > 0; off >>= 1)
        sum += __shfl_down(sum, off, 64);

    __shared__ float wsum[NTHREADS / 64];
    const int lane = threadIdx.x & 63;
    const int wave = threadIdx.x >> 6;
    if (lane == 0) wsum[wave] = sum;
    __syncthreads();
    if (threadIdx.x == 0) {
        float s = 0.0f;
        #pragma unroll
        for (int w = 0; w < NTHREADS / 64; ++w) s += wsum[w];
        out[0] = s / (float)nrows;
    }
}

extern "C" void kernel_launch(void* const* d_in, const int* in_sizes, int n_in,
                              void* d_out, int out_size, void* d_ws, size_t ws_size,
                              hipStream_t stream) {
    const float* inputs  = (const float*)d_in[0];
    const float* targets = (const float*)d_in[1];
    float* out = (float*)d_out;
    float* partial = (float*)d_ws;   // NBLOCKS floats

    const long long nrows = (long long)in_sizes[0] / 5;

    loss_partial<<<NBLOCKS, NTHREADS, 0, stream>>>(inputs, targets, partial, nrows);
    loss_final<<<1, NTHREADS, 0, stream>>>(partial, NBLOCKS, out, nrows);
}